// Round 18
// baseline (113.458 us; speedup 1.0000x reference)
//
#include <hip/hip_runtime.h>
#include <hip/hip_bf16.h>
#include <stdint.h>

#define D_IN   1024
#define D_OUT  1024
#define NHEAD  16
#define HDIM   64
#define SEQ    2048
#define BATCH  2
#define M_TOT  (BATCH*SEQ)   // 4096

typedef __attribute__((ext_vector_type(8)))  short bfx8;   // 8 bf16
typedef __attribute__((ext_vector_type(4)))  short bfx4;   // 4 bf16
typedef __attribute__((ext_vector_type(4)))  float fx4;
typedef __attribute__((ext_vector_type(16))) float fx16;
typedef unsigned short u16;
typedef unsigned int   u32;

__device__ __forceinline__ u16 f2bf(float f) {
    u32 u = __builtin_bit_cast(u32, f);
    u32 r = (u + 0x7FFFu + ((u >> 16) & 1u)) >> 16;   // RNE
    return (u16)r;
}
__device__ __forceinline__ float bf2f(u16 v) {
    u32 u = (u32)v << 16;
    return __builtin_bit_cast(float, u);
}

__device__ __forceinline__ u32 cvtpk(float lo, float hi) {
    u32 r;
    asm("v_cvt_pk_bf16_f32 %0, %1, %2" : "=v"(r) : "v"(lo), "v"(hi));
    return r;
}

__device__ __forceinline__ float exp2x(float x) {   // 2^x, single v_exp_f32
    float r;
    asm("v_exp_f32 %0, %1" : "=v"(r) : "v"(x));
    return r;
}

// async global -> LDS, 16B per lane. LDS dest = wave-uniform base + lane*16.
__device__ __forceinline__ void gload16(const u16* g, u16* l) {
    __builtin_amdgcn_global_load_lds(
        (const __attribute__((address_space(1))) void*)g,
        (__attribute__((address_space(3))) void*)l, 16, 0, 0);
}

// ---------------- x fp32 -> bf16 ----------------
__global__ void k_conv_x(const float* __restrict__ x, u16* __restrict__ xb) {
    int i = blockIdx.x * 256 + threadIdx.x;
    const float4* s = reinterpret_cast<const float4*>(x);
    float4 a = s[2*i], b = s[2*i+1];
    uint4 o;
    o.x = (u32)f2bf(a.x) | ((u32)f2bf(a.y) << 16);
    o.y = (u32)f2bf(a.z) | ((u32)f2bf(a.w) << 16);
    o.z = (u32)f2bf(b.x) | ((u32)f2bf(b.y) << 16);
    o.w = (u32)f2bf(b.z) | ((u32)f2bf(b.w) << 16);
    reinterpret_cast<uint4*>(xb)[i] = o;
}

// ------------- W fp32 -> bf16, transposed (Wt[n][k] = W[k][n]) -------------
// Wq pre-scaled by 0.125*log2(e) so attention uses raw v_exp_f32 (2^x).
__global__ void k_conv_wt(const float* __restrict__ Wq, const float* __restrict__ Wk,
                          const float* __restrict__ Wv, const float* __restrict__ Wo,
                          u16* __restrict__ wt) {
    __shared__ float tile[32][33];
    int wsel = blockIdx.z;
    const float* W = (wsel == 0) ? Wq : (wsel == 1) ? Wk : (wsel == 2) ? Wv : Wo;
    const float scale = (wsel == 0) ? 0.125f * 1.4426950408889634f : 1.0f;
    u16* dst = wt + (size_t)wsel * D_IN * D_OUT;
    int r0 = blockIdx.y * 32, c0 = blockIdx.x * 32;
    int tx = threadIdx.x & 31, ty = threadIdx.x >> 5;
    #pragma unroll
    for (int k = 0; k < 4; k++) {
        int i = ty + k * 8;
        tile[i][tx] = W[(size_t)(r0 + i) * D_OUT + c0 + tx];
    }
    __syncthreads();
    #pragma unroll
    for (int k = 0; k < 4; k++) {
        int i = ty + k * 8;
        dst[(size_t)(c0 + i) * D_IN + r0 + tx] = f2bf(tile[tx][i] * scale);
    }
}

// ---------------- 128x128 GEMM, BK=64, XOR-swizzled LDS — QKV ----------------
// BK 32->64 halves barrier/waitcnt events per FLOP; attn-style XOR swizzle
// (slot j of row r holds chunk j^(r&7); read col ^= (row&7)*8) keeps b128
// reads at a free 2-way conflict (linear BK=64 would be 16-way).
__global__ __launch_bounds__(256) void k_qkv(const u16* __restrict__ A,
                                             const u16* __restrict__ Bt,
                                             u16* __restrict__ outb) {
    __shared__ u16 aL[128][64];
    __shared__ u16 bL[128][64];
    const int K = 1024;
    const int nb = blockIdx.x * 128, mb = blockIdx.y * 128;
    const int t = threadIdx.x, lane = t & 63, w = t >> 6;
    const int wr = w >> 1, wc = w & 1;
    const int li = lane & 15, lg = lane >> 4;
    const int srow = lane >> 3;                 // 0..7
    const int ts = (lane & 7) ^ srow;           // pre-swizzled source chunk

    fx4 acc[4][4];
    #pragma unroll
    for (int i = 0; i < 4; i++)
        #pragma unroll
        for (int j = 0; j < 4; j++) acc[i][j] = fx4{0.f, 0.f, 0.f, 0.f};

    const u16* aBase = A  + (size_t)(mb + w * 32 + srow) * K + ts * 8;
    const u16* bBase = Bt + (size_t)(nb + w * 32 + srow) * K + ts * 8;

    for (int kb = 0; kb < K; kb += 64) {
        #pragma unroll
        for (int i = 0; i < 4; i++) {
            gload16(aBase + (size_t)i * 8 * K + kb, &aL[w * 32 + i * 8][0]);
            gload16(bBase + (size_t)i * 8 * K + kb, &bL[w * 32 + i * 8][0]);
        }
        __syncthreads();
        bfx8 af[4][2], bf[4][2];
        #pragma unroll
        for (int mi = 0; mi < 4; mi++) {
            const int row = wr * 64 + mi * 16 + li;
            #pragma unroll
            for (int kh = 0; kh < 2; kh++)
                af[mi][kh] = *reinterpret_cast<const bfx8*>(
                    &aL[row][((kh * 4 + lg) ^ (row & 7)) * 8]);
        }
        #pragma unroll
        for (int ni = 0; ni < 4; ni++) {
            const int row = wc * 64 + ni * 16 + li;
            #pragma unroll
            for (int kh = 0; kh < 2; kh++)
                bf[ni][kh] = *reinterpret_cast<const bfx8*>(
                    &bL[row][((kh * 4 + lg) ^ (row & 7)) * 8]);
        }
        #pragma unroll
        for (int kh = 0; kh < 2; kh++)
            #pragma unroll
            for (int mi = 0; mi < 4; mi++)
                #pragma unroll
                for (int ni = 0; ni < 4; ni++)
                    acc[mi][ni] = __builtin_amdgcn_mfma_f32_16x16x32_bf16(
                        af[mi][kh], bf[ni][kh], acc[mi][ni], 0, 0, 0);
        __syncthreads();
    }

    #pragma unroll
    for (int mi = 0; mi < 4; mi++) {
        #pragma unroll
        for (int ni = 0; ni < 4; ni++) {
            const int n = nb + wc * 64 + ni * 16 + li;
            const int m0 = mb + wr * 64 + mi * 16 + lg * 4;
            const int proj = n >> 10, h = (n >> 6) & 15, d = n & 63;
            const int b = m0 >> 11, s0 = m0 & 2047;
            if (proj == 2) {
                u16* op = outb + (size_t)2 * M_TOT * D_OUT +
                          ((size_t)(b * NHEAD + h) * HDIM + d) * SEQ + s0;
                bfx4 pk = {(short)f2bf(acc[mi][ni][0]), (short)f2bf(acc[mi][ni][1]),
                           (short)f2bf(acc[mi][ni][2]), (short)f2bf(acc[mi][ni][3])};
                *reinterpret_cast<bfx4*>(op) = pk;
            } else {
                u16* op = outb + (size_t)proj * M_TOT * D_OUT;
                #pragma unroll
                for (int r = 0; r < 4; r++)
                    op[((size_t)(b * NHEAD + h) * SEQ + s0 + r) * HDIM + d] =
                        f2bf(acc[mi][ni][r]);
            }
        }
    }
}

// ---------------- output projection: 128(M) x 64(N), BK=64, swizzled ----------
__global__ __launch_bounds__(256) void k_oproj(const u16* __restrict__ A,
                                               const u16* __restrict__ Bt,
                                               const float* __restrict__ bias,
                                               float* __restrict__ outf) {
    __shared__ u16 aL[128][64];
    __shared__ u16 bL[64][64];
    const int K = 1024;
    const int nb = blockIdx.x * 64, mb = blockIdx.y * 128;
    const int t = threadIdx.x, lane = t & 63, w = t >> 6;
    const int wr = w >> 1, wc = w & 1;
    const int li = lane & 15, lg = lane >> 4;
    const int srow = lane >> 3;
    const int ts = (lane & 7) ^ srow;

    fx4 acc[4][2];
    #pragma unroll
    for (int i = 0; i < 4; i++)
        #pragma unroll
        for (int j = 0; j < 2; j++) acc[i][j] = fx4{0.f, 0.f, 0.f, 0.f};

    const u16* aBase = A  + (size_t)(mb + w * 32 + srow) * K + ts * 8;
    const u16* bBase = Bt + (size_t)(nb + w * 16 + srow) * K + ts * 8;

    for (int kb = 0; kb < K; kb += 64) {
        #pragma unroll
        for (int i = 0; i < 4; i++)
            gload16(aBase + (size_t)i * 8 * K + kb, &aL[w * 32 + i * 8][0]);
        #pragma unroll
        for (int i = 0; i < 2; i++)
            gload16(bBase + (size_t)i * 8 * K + kb, &bL[w * 16 + i * 8][0]);
        __syncthreads();
        bfx8 af[4][2], bf[2][2];
        #pragma unroll
        for (int mi = 0; mi < 4; mi++) {
            const int row = wr * 64 + mi * 16 + li;
            #pragma unroll
            for (int kh = 0; kh < 2; kh++)
                af[mi][kh] = *reinterpret_cast<const bfx8*>(
                    &aL[row][((kh * 4 + lg) ^ (row & 7)) * 8]);
        }
        #pragma unroll
        for (int ni = 0; ni < 2; ni++) {
            const int row = wc * 32 + ni * 16 + li;
            #pragma unroll
            for (int kh = 0; kh < 2; kh++)
                bf[ni][kh] = *reinterpret_cast<const bfx8*>(
                    &bL[row][((kh * 4 + lg) ^ (row & 7)) * 8]);
        }
        #pragma unroll
        for (int kh = 0; kh < 2; kh++)
            #pragma unroll
            for (int mi = 0; mi < 4; mi++)
                #pragma unroll
                for (int ni = 0; ni < 2; ni++)
                    acc[mi][ni] = __builtin_amdgcn_mfma_f32_16x16x32_bf16(
                        af[mi][kh], bf[ni][kh], acc[mi][ni], 0, 0, 0);
        __syncthreads();
    }

    #pragma unroll
    for (int mi = 0; mi < 4; mi++) {
        #pragma unroll
        for (int ni = 0; ni < 2; ni++) {
            const int n = nb + wc * 32 + ni * 16 + li;
            const int m0 = mb + wr * 64 + mi * 16 + lg * 4;
            const float bv = bias[n];
            #pragma unroll
            for (int r = 0; r < 4; r++)
                outf[(size_t)(m0 + r) * D_OUT + n] = acc[mi][ni][r] + bv;
        }
    }
}

// ---------------- causal flash attention (8-wave, 3-buffer, 1 barrier/tile) ------
// Round-16/17 math; sync restructured: 3-buffer rotation with stage issued at
// END of the body -> ONE barrier per tile (stage target (tt+2)%3 is disjoint
// from the buffers readable by any wave: readers span body tt only, so only
// buf[tt%3] is read and buf[(tt+1)%3] is pending). Counted vmcnt(2).
// T5 setprio(1) around both MFMA clusters (8-wave role diversity).
__global__ __launch_bounds__(512, 2) void k_attn(const u16* __restrict__ Q,
                                                 const u16* __restrict__ Kp,
                                                 const u16* __restrict__ Vt,
                                                 u16* __restrict__ ctx,
                                                 u16* __restrict__ o1,
                                                 float* __restrict__ l0,
                                                 float* __restrict__ l1) {
    __shared__ u16 kbuf[3][64][64];   // K tile [kv][d], swizzled slots (24KB)
    __shared__ u16 vbuf[3][64][64];   // V^T tile [d][kv], swizzled slots (24KB)

    static const __constant__ signed char QT[12]   = {7,7,6,6,5,5,4,4,3,2,1,0};
    static const __constant__ signed char PART[12] = {0,1,0,1,0,1,0,1,0,0,0,0};

    const int g  = blockIdx.x;                   // 0..383
    const int m  = g & 31, pp = g >> 5;          // pp 0..11
    const int bh = (m & 7) * 4 + (m >> 3);       // 4 heads per XCD
    const int qt = QT[pp], part = PART[pp];
    const bool heavy = (qt >= 4);
    const int nt = 4 * qt + 4;
    int t0, t1;
    if (heavy) { int h1 = nt >> 1; t0 = part ? h1 : 0; t1 = part ? nt : h1; }
    else       { t0 = 0; t1 = nt; }
    const int ntL = t1 - t0;                     // <= 16

    const size_t base = (size_t)bh * SEQ * HDIM;
    const int t = threadIdx.x, lane = t & 63, w = t >> 6;   // w 0..7
    const int l31 = lane & 31, hi = lane >> 5;
    const int srow = lane >> 3;
    const int ts = (lane & 7) ^ srow;
    const int bq = bh >> 4, hh = bh & 15;
    const int swz = (l31 & 7) * 8;
    const int qwb = qt * 256 + w * 32;
    const int qg  = qwb + l31;

    // stage one 64-kv tile (K 8KB + V^T 8KB); 2 gload16 per wave (8 waves)
    auto stage = [&](int bi, int kvb) {
        const int rb = w * 8;
        gload16(Kp + base + (size_t)(kvb + rb + srow) * HDIM + ts * 8,
                &kbuf[bi][rb][0]);
        gload16(Vt + base + (size_t)(rb + srow) * SEQ + kvb + ts * 8,
                &vbuf[bi][rb][0]);
    };

    bfx8 qf[4];
    #pragma unroll
    for (int dc = 0; dc < 4; dc++)
        qf[dc] = *reinterpret_cast<const bfx8*>(
            &Q[base + (size_t)qg * HDIM + dc * 16 + hi * 8]);
    fx16 cacc[2];
    #pragma unroll
    for (int dt = 0; dt < 2; dt++)
        #pragma unroll
        for (int r = 0; r < 16; r++) cacc[dt][r] = 0.f;
    float lsum = 0.f;

    stage(0, t0 * 64);
    if (ntL > 1) stage(1, (t0 + 1) * 64);

    for (int tt = 0; tt < ntL; tt++) {
        const int ti = t0 + tt, kvb = ti * 64;
        if (tt + 1 < ntL) {
            asm volatile("s_waitcnt vmcnt(2)" ::: "memory");  // stage(tt) landed
        } else {
            asm volatile("s_waitcnt vmcnt(0)" ::: "memory");
        }
        __builtin_amdgcn_s_barrier();
        __builtin_amdgcn_sched_barrier(0);
        const int bi = tt % 3;
        if (kvb <= qwb + 31) {                   // wave-level causal skip
            // ---- S^T = K · Q^T (rows=kv, cols=q) ----
            fx16 sc[2];
            __builtin_amdgcn_s_setprio(1);
            #pragma unroll
            for (int s = 0; s < 2; s++) {
                #pragma unroll
                for (int r = 0; r < 16; r++) sc[s][r] = 0.f;
                #pragma unroll
                for (int dc = 0; dc < 4; dc++) {
                    bfx8 kf = *reinterpret_cast<const bfx8*>(
                        &kbuf[bi][s * 32 + l31][(dc * 16 + hi * 8) ^ swz]);
                    sc[s] = __builtin_amdgcn_mfma_f32_32x32x16_bf16(kf, qf[dc], sc[s], 0, 0, 0);
                }
            }
            __builtin_amdgcn_s_setprio(0);
            // causal mask (diagonal tile only; scores pre-scaled by 0.125*log2e)
            if (kvb + 63 > qwb) {
                #pragma unroll
                for (int s = 0; s < 2; s++)
                    #pragma unroll
                    for (int r = 0; r < 16; r++) {
                        int kvg = kvb + s * 32 + (r & 3) + 8 * (r >> 2) + 4 * hi;
                        if (kvg > qg) sc[s][r] = -1e30f;
                    }
            }
            // P = 2^S, row-sum
            float ps = 0.f;
            #pragma unroll
            for (int s = 0; s < 2; s++)
                #pragma unroll
                for (int r = 0; r < 16; r++) {
                    float pv = exp2x(sc[s][r]);
                    sc[s][r] = pv;
                    ps += pv;
                }
            lsum += ps;
            // ---- pack P to bf16, lane-pair exchange, PV ----
            #pragma unroll
            for (int c = 0; c < 4; c++) {
                const int s = c >> 1, rb_ = (c & 1) * 8;
                u32 a0 = cvtpk(sc[s][rb_ + 0], sc[s][rb_ + 1]);
                u32 a1 = cvtpk(sc[s][rb_ + 2], sc[s][rb_ + 3]);
                u32 b0 = cvtpk(sc[s][rb_ + 4], sc[s][rb_ + 5]);
                u32 b1 = cvtpk(sc[s][rb_ + 6], sc[s][rb_ + 7]);
                u32 X0 = hi ? a0 : b0, X1 = hi ? a1 : b1;
                u32 Y0 = (u32)__shfl_xor((int)X0, 32);
                u32 Y1 = (u32)__shfl_xor((int)X1, 32);
                uint4 pw;
                pw.x = hi ? Y0 : a0;
                pw.y = hi ? Y1 : a1;
                pw.z = hi ? b0 : Y0;
                pw.w = hi ? b1 : Y1;
                bfx8 pf = __builtin_bit_cast(bfx8, pw);
                __builtin_amdgcn_s_setprio(1);
                #pragma unroll
                for (int dt = 0; dt < 2; dt++) {
                    bfx8 vf = *reinterpret_cast<const bfx8*>(
                        &vbuf[bi][dt * 32 + l31][(c * 16 + hi * 8) ^ swz]);
                    cacc[dt] = __builtin_amdgcn_mfma_f32_32x32x16_bf16(pf, vf, cacc[dt], 0, 0, 0);
                }
                __builtin_amdgcn_s_setprio(0);
            }
        }
        // stage at END: target (tt+2)%3 is neither the buffer any wave reads
        // now (tt%3) nor the pending one ((tt+1)%3).
        if (tt + 2 < ntL) stage((tt + 2) % 3, (ti + 2) * 64);
    }

    float ltot = lsum + __shfl_xor(lsum, 32);
    if (!heavy) {
        float linv = 1.0f / ltot;
        #pragma unroll
        for (int r = 0; r < 16; r++) {
            const int qpat = (r & 3) + 8 * (r >> 2) + 4 * hi;
            float rl = __shfl(linv, qpat);
            const int q = qwb + qpat;
            #pragma unroll
            for (int dt = 0; dt < 2; dt++)
                ctx[((size_t)(bq * SEQ + q)) * D_OUT + hh * HDIM + dt * 32 + l31] =
                    f2bf(cacc[dt][r] * rl);
        }
    } else {
        const int qt4 = qt - 4;
        const int rbase = (qt4 * 32 + bh) * 256 + w * 32;
        if (hi == 0) { (part ? l1 : l0)[rbase + l31] = ltot; }
        #pragma unroll
        for (int r = 0; r < 16; r++) {
            const int qpat = (r & 3) + 8 * (r >> 2) + 4 * hi;
            const int q = qwb + qpat;
            #pragma unroll
            for (int dt = 0; dt < 2; dt++) {
                const int d = dt * 32 + l31;
                u16 val = f2bf(cacc[dt][r]);
                if (part == 0)
                    ctx[((size_t)(bq * SEQ + q)) * D_OUT + hh * HDIM + d] = val;
                else
                    o1[((size_t)(rbase + qpat)) * 64 + d] = val;
            }
        }
    }
}

// ---------------- combine heavy partials: ctx = (O0+O1)/(l0+l1) ----------------
__global__ void k_comb(u16* __restrict__ ctx, const u16* __restrict__ o1,
                       const float* __restrict__ l0, const float* __restrict__ l1) {
    int i = blockIdx.x * 256 + threadIdx.x;
    const int d    = (i & 7) * 8;
    const int qrow = (i >> 3) & 255;
    const int bi_  = i >> 11;
    const int bh   = bi_ & 31, qt4 = bi_ >> 5;
    const int bq = bh >> 4, hh = bh & 15;
    const int token = bq * SEQ + (4 + qt4) * 256 + qrow;
    const size_t cidx = (size_t)token * D_OUT + hh * HDIM + d;
    const int ridx = bi_ * 256 + qrow;
    const size_t oidx = (size_t)ridx * 64 + d;
    const float linv = 1.0f / (l0[ridx] + l1[ridx]);
    bfx8 a = *reinterpret_cast<const bfx8*>(&ctx[cidx]);
    bfx8 b = *reinterpret_cast<const bfx8*>(&o1[oidx]);
    bfx8 o;
    #pragma unroll
    for (int j = 0; j < 8; j++)
        o[j] = (short)f2bf((bf2f((u16)a[j]) + bf2f((u16)b[j])) * linv);
    *reinterpret_cast<bfx8*>(&ctx[cidx]) = o;
}

extern "C" void kernel_launch(void* const* d_in, const int* in_sizes, int n_in,
                              void* d_out, int out_size, void* d_ws, size_t ws_size,
                              hipStream_t stream) {
    const float* x  = (const float*)d_in[0];
    const float* Wq = (const float*)d_in[1];
    const float* Wk = (const float*)d_in[2];
    const float* Wv = (const float*)d_in[3];
    const float* Wo = (const float*)d_in[4];
    const float* bo = (const float*)d_in[5];
    float* out = (float*)d_out;

    char* ws = (char*)d_ws;
    u16* xb   = (u16*)(ws);                    //  8 MiB: x bf16 (reused for partials)
    u16* wt   = (u16*)(ws + (8u << 20));       //  8 MiB: W transposed bf16
    u16* qkvb = (u16*)(ws + (16u << 20));      // 24 MiB: Q,K [bh][s][d]; V^T [bh][d][s]
    u16* ctxb = (u16*)(ws + (40u << 20));      //  8 MiB: ctx bf16

    u16*   o1p = (u16*)(ws);                   // 4 MiB: part1 O bf16
    float* l0p = (float*)(ws + (4u << 20));    // 128 KiB
    float* l1p = (float*)(ws + (4u << 20) + (128u << 10));

    const u16* Qb  = qkvb;
    const u16* Kb  = qkvb + (size_t)M_TOT * D_OUT;
    const u16* Vtb = qkvb + (size_t)2 * M_TOT * D_OUT;

    k_conv_x <<<2048, 256, 0, stream>>>(x, xb);
    k_conv_wt<<<dim3(32, 32, 4), 256, 0, stream>>>(Wq, Wk, Wv, Wo, wt);
    k_qkv    <<<dim3(24, 32), 256, 0, stream>>>(xb, wt, qkvb);
    k_attn   <<<dim3(384), 512, 0, stream>>>(Qb, Kb, Vtb, ctxb, o1p, l0p, l1p);
    k_comb   <<<1024, 256, 0, stream>>>(ctxb, o1p, l0p, l1p);
    k_oproj  <<<dim3(16, 32), 256, 0, stream>>>(
        ctxb, wt + (size_t)3 * D_IN * D_OUT, bo, out);
}

// Round 19
// 111.131 us; speedup vs baseline: 1.0209x; 1.0209x over previous
//
#include <hip/hip_runtime.h>
#include <hip/hip_bf16.h>
#include <stdint.h>

#define D_IN   1024
#define D_OUT  1024
#define NHEAD  16
#define HDIM   64
#define SEQ    2048
#define BATCH  2
#define M_TOT  (BATCH*SEQ)   // 4096

typedef __attribute__((ext_vector_type(8)))  short bfx8;   // 8 bf16
typedef __attribute__((ext_vector_type(4)))  short bfx4;   // 4 bf16
typedef __attribute__((ext_vector_type(4)))  float fx4;
typedef __attribute__((ext_vector_type(16))) float fx16;
typedef unsigned short u16;
typedef unsigned int   u32;

__device__ __forceinline__ u16 f2bf(float f) {
    u32 u = __builtin_bit_cast(u32, f);
    u32 r = (u + 0x7FFFu + ((u >> 16) & 1u)) >> 16;   // RNE
    return (u16)r;
}
__device__ __forceinline__ float bf2f(u16 v) {
    u32 u = (u32)v << 16;
    return __builtin_bit_cast(float, u);
}

__device__ __forceinline__ u32 cvtpk(float lo, float hi) {
    u32 r;
    asm("v_cvt_pk_bf16_f32 %0, %1, %2" : "=v"(r) : "v"(lo), "v"(hi));
    return r;
}

__device__ __forceinline__ float exp2x(float x) {   // 2^x, single v_exp_f32
    float r;
    asm("v_exp_f32 %0, %1" : "=v"(r) : "v"(x));
    return r;
}

// async global -> LDS, 16B per lane. LDS dest = wave-uniform base + lane*16.
__device__ __forceinline__ void gload16(const u16* g, u16* l) {
    __builtin_amdgcn_global_load_lds(
        (const __attribute__((address_space(1))) void*)g,
        (__attribute__((address_space(3))) void*)l, 16, 0, 0);
}

// ---------------- x fp32 -> bf16 ----------------
__global__ void k_conv_x(const float* __restrict__ x, u16* __restrict__ xb) {
    int i = blockIdx.x * 256 + threadIdx.x;
    const float4* s = reinterpret_cast<const float4*>(x);
    float4 a = s[2*i], b = s[2*i+1];
    uint4 o;
    o.x = (u32)f2bf(a.x) | ((u32)f2bf(a.y) << 16);
    o.y = (u32)f2bf(a.z) | ((u32)f2bf(a.w) << 16);
    o.z = (u32)f2bf(b.x) | ((u32)f2bf(b.y) << 16);
    o.w = (u32)f2bf(b.z) | ((u32)f2bf(b.w) << 16);
    reinterpret_cast<uint4*>(xb)[i] = o;
}

// ------------- W fp32 -> bf16, transposed (Wt[n][k] = W[k][n]) -------------
// Wq pre-scaled by 0.125*log2(e) so attention uses raw v_exp_f32 (2^x).
__global__ void k_conv_wt(const float* __restrict__ Wq, const float* __restrict__ Wk,
                          const float* __restrict__ Wv, const float* __restrict__ Wo,
                          u16* __restrict__ wt) {
    __shared__ float tile[32][33];
    int wsel = blockIdx.z;
    const float* W = (wsel == 0) ? Wq : (wsel == 1) ? Wk : (wsel == 2) ? Wv : Wo;
    const float scale = (wsel == 0) ? 0.125f * 1.4426950408889634f : 1.0f;
    u16* dst = wt + (size_t)wsel * D_IN * D_OUT;
    int r0 = blockIdx.y * 32, c0 = blockIdx.x * 32;
    int tx = threadIdx.x & 31, ty = threadIdx.x >> 5;
    #pragma unroll
    for (int k = 0; k < 4; k++) {
        int i = ty + k * 8;
        tile[i][tx] = W[(size_t)(r0 + i) * D_OUT + c0 + tx];
    }
    __syncthreads();
    #pragma unroll
    for (int k = 0; k < 4; k++) {
        int i = ty + k * 8;
        dst[(size_t)(c0 + i) * D_IN + r0 + tx] = f2bf(tile[tx][i] * scale);
    }
}

// ---------------- 128x128 GEMM (m97 structure, round-17 version) — QKV ----------
__global__ __launch_bounds__(256) void k_qkv(const u16* __restrict__ A,
                                             const u16* __restrict__ Bt,
                                             u16* __restrict__ outb) {
    __shared__ u16 aL[128][32];
    __shared__ u16 bL[128][32];
    const int K = 1024;
    const int nb = blockIdx.x * 128, mb = blockIdx.y * 128;
    const int t = threadIdx.x, lane = t & 63, w = t >> 6;
    const int wr = w >> 1, wc = w & 1;
    const int li = lane & 15, lg = lane >> 4;
    const int srow = lane >> 2, schunk = (lane & 3) * 8;

    fx4 acc[4][4];
    #pragma unroll
    for (int i = 0; i < 4; i++)
        #pragma unroll
        for (int j = 0; j < 4; j++) acc[i][j] = fx4{0.f, 0.f, 0.f, 0.f};

    const u16* aBase = A  + (size_t)(mb + w * 32 + srow) * K + schunk;
    const u16* bBase = Bt + (size_t)(nb + w * 32 + srow) * K + schunk;

    for (int kb = 0; kb < K; kb += 32) {
        #pragma unroll
        for (int c = 0; c < 2; c++) {
            gload16(aBase + (size_t)c * 16 * K + kb, &aL[w * 32 + c * 16][0]);
            gload16(bBase + (size_t)c * 16 * K + kb, &bL[w * 32 + c * 16][0]);
        }
        __syncthreads();
        bfx8 af[4], bf[4];
        #pragma unroll
        for (int mi = 0; mi < 4; mi++)
            af[mi] = *reinterpret_cast<const bfx8*>(&aL[wr * 64 + mi * 16 + li][lg * 8]);
        #pragma unroll
        for (int ni = 0; ni < 4; ni++)
            bf[ni] = *reinterpret_cast<const bfx8*>(&bL[wc * 64 + ni * 16 + li][lg * 8]);
        #pragma unroll
        for (int mi = 0; mi < 4; mi++)
            #pragma unroll
            for (int ni = 0; ni < 4; ni++)
                acc[mi][ni] = __builtin_amdgcn_mfma_f32_16x16x32_bf16(af[mi], bf[ni], acc[mi][ni], 0, 0, 0);
        __syncthreads();
    }

    #pragma unroll
    for (int mi = 0; mi < 4; mi++) {
        #pragma unroll
        for (int ni = 0; ni < 4; ni++) {
            const int n = nb + wc * 64 + ni * 16 + li;
            const int m0 = mb + wr * 64 + mi * 16 + lg * 4;
            const int proj = n >> 10, h = (n >> 6) & 15, d = n & 63;
            const int b = m0 >> 11, s0 = m0 & 2047;
            if (proj == 2) {
                u16* op = outb + (size_t)2 * M_TOT * D_OUT +
                          ((size_t)(b * NHEAD + h) * HDIM + d) * SEQ + s0;
                bfx4 pk = {(short)f2bf(acc[mi][ni][0]), (short)f2bf(acc[mi][ni][1]),
                           (short)f2bf(acc[mi][ni][2]), (short)f2bf(acc[mi][ni][3])};
                *reinterpret_cast<bfx4*>(op) = pk;
            } else {
                u16* op = outb + (size_t)proj * M_TOT * D_OUT;
                #pragma unroll
                for (int r = 0; r < 4; r++)
                    op[((size_t)(b * NHEAD + h) * SEQ + s0 + r) * HDIM + d] =
                        f2bf(acc[mi][ni][r]);
            }
        }
    }
}

// ---------------- output projection: 128(M) x 64(N) tiles (round-17) ----------
__global__ __launch_bounds__(256) void k_oproj(const u16* __restrict__ A,
                                               const u16* __restrict__ Bt,
                                               const float* __restrict__ bias,
                                               float* __restrict__ outf) {
    __shared__ u16 aL[128][32];
    __shared__ u16 bL[64][32];
    const int K = 1024;
    const int nb = blockIdx.x * 64, mb = blockIdx.y * 128;
    const int t = threadIdx.x, lane = t & 63, w = t >> 6;
    const int wr = w >> 1, wc = w & 1;
    const int li = lane & 15, lg = lane >> 4;
    const int srow = lane >> 2, schunk = (lane & 3) * 8;

    fx4 acc[4][2];
    #pragma unroll
    for (int i = 0; i < 4; i++)
        #pragma unroll
        for (int j = 0; j < 2; j++) acc[i][j] = fx4{0.f, 0.f, 0.f, 0.f};

    const u16* aBase = A  + (size_t)(mb + w * 32 + srow) * K + schunk;
    const u16* bBase = Bt + (size_t)(nb + w * 16 + srow) * K + schunk;

    for (int kb = 0; kb < K; kb += 32) {
        gload16(aBase + kb,          &aL[w * 32][0]);
        gload16(aBase + 16 * K + kb, &aL[w * 32 + 16][0]);
        gload16(bBase + kb,          &bL[w * 16][0]);
        __syncthreads();
        bfx8 af[4], bf[2];
        #pragma unroll
        for (int mi = 0; mi < 4; mi++)
            af[mi] = *reinterpret_cast<const bfx8*>(&aL[wr * 64 + mi * 16 + li][lg * 8]);
        #pragma unroll
        for (int ni = 0; ni < 2; ni++)
            bf[ni] = *reinterpret_cast<const bfx8*>(&bL[wc * 32 + ni * 16 + li][lg * 8]);
        #pragma unroll
        for (int mi = 0; mi < 4; mi++)
            #pragma unroll
            for (int ni = 0; ni < 2; ni++)
                acc[mi][ni] = __builtin_amdgcn_mfma_f32_16x16x32_bf16(af[mi], bf[ni], acc[mi][ni], 0, 0, 0);
        __syncthreads();
    }

    #pragma unroll
    for (int mi = 0; mi < 4; mi++) {
        #pragma unroll
        for (int ni = 0; ni < 2; ni++) {
            const int n = nb + wc * 32 + ni * 16 + li;
            const int m0 = mb + wr * 64 + mi * 16 + lg * 4;
            const float bv = bias[n];
            #pragma unroll
            for (int r = 0; r < 4; r++)
                outf[(size_t)(m0 + r) * D_OUT + n] = acc[mi][ni][r] + bv;
        }
    }
}

// ---------------- causal flash attention (8-wave, 3-buffer, 1 barrier/tile) ------
// Round-18 version (kept: -7us vs round-17). 3-buffer rotation, stage at END,
// ONE barrier/tile, counted vmcnt(2), T5 setprio around MFMA clusters.
__global__ __launch_bounds__(512, 2) void k_attn(const u16* __restrict__ Q,
                                                 const u16* __restrict__ Kp,
                                                 const u16* __restrict__ Vt,
                                                 u16* __restrict__ ctx,
                                                 u16* __restrict__ o1,
                                                 float* __restrict__ l0,
                                                 float* __restrict__ l1) {
    __shared__ u16 kbuf[3][64][64];   // K tile [kv][d], swizzled slots (24KB)
    __shared__ u16 vbuf[3][64][64];   // V^T tile [d][kv], swizzled slots (24KB)

    static const __constant__ signed char QT[12]   = {7,7,6,6,5,5,4,4,3,2,1,0};
    static const __constant__ signed char PART[12] = {0,1,0,1,0,1,0,1,0,0,0,0};

    const int g  = blockIdx.x;                   // 0..383
    const int m  = g & 31, pp = g >> 5;          // pp 0..11
    const int bh = (m & 7) * 4 + (m >> 3);       // 4 heads per XCD
    const int qt = QT[pp], part = PART[pp];
    const bool heavy = (qt >= 4);
    const int nt = 4 * qt + 4;
    int t0, t1;
    if (heavy) { int h1 = nt >> 1; t0 = part ? h1 : 0; t1 = part ? nt : h1; }
    else       { t0 = 0; t1 = nt; }
    const int ntL = t1 - t0;                     // <= 16

    const size_t base = (size_t)bh * SEQ * HDIM;
    const int t = threadIdx.x, lane = t & 63, w = t >> 6;   // w 0..7
    const int l31 = lane & 31, hi = lane >> 5;
    const int srow = lane >> 3;
    const int ts = (lane & 7) ^ srow;
    const int bq = bh >> 4, hh = bh & 15;
    const int swz = (l31 & 7) * 8;
    const int qwb = qt * 256 + w * 32;
    const int qg  = qwb + l31;

    auto stage = [&](int bi, int kvb) {
        const int rb = w * 8;
        gload16(Kp + base + (size_t)(kvb + rb + srow) * HDIM + ts * 8,
                &kbuf[bi][rb][0]);
        gload16(Vt + base + (size_t)(rb + srow) * SEQ + kvb + ts * 8,
                &vbuf[bi][rb][0]);
    };

    bfx8 qf[4];
    #pragma unroll
    for (int dc = 0; dc < 4; dc++)
        qf[dc] = *reinterpret_cast<const bfx8*>(
            &Q[base + (size_t)qg * HDIM + dc * 16 + hi * 8]);
    fx16 cacc[2];
    #pragma unroll
    for (int dt = 0; dt < 2; dt++)
        #pragma unroll
        for (int r = 0; r < 16; r++) cacc[dt][r] = 0.f;
    float lsum = 0.f;

    stage(0, t0 * 64);
    if (ntL > 1) stage(1, (t0 + 1) * 64);

    for (int tt = 0; tt < ntL; tt++) {
        const int ti = t0 + tt, kvb = ti * 64;
        if (tt + 1 < ntL) {
            asm volatile("s_waitcnt vmcnt(2)" ::: "memory");  // stage(tt) landed
        } else {
            asm volatile("s_waitcnt vmcnt(0)" ::: "memory");
        }
        __builtin_amdgcn_s_barrier();
        __builtin_amdgcn_sched_barrier(0);
        const int bi = tt % 3;
        if (kvb <= qwb + 31) {                   // wave-level causal skip
            fx16 sc[2];
            __builtin_amdgcn_s_setprio(1);
            #pragma unroll
            for (int s = 0; s < 2; s++) {
                #pragma unroll
                for (int r = 0; r < 16; r++) sc[s][r] = 0.f;
                #pragma unroll
                for (int dc = 0; dc < 4; dc++) {
                    bfx8 kf = *reinterpret_cast<const bfx8*>(
                        &kbuf[bi][s * 32 + l31][(dc * 16 + hi * 8) ^ swz]);
                    sc[s] = __builtin_amdgcn_mfma_f32_32x32x16_bf16(kf, qf[dc], sc[s], 0, 0, 0);
                }
            }
            __builtin_amdgcn_s_setprio(0);
            if (kvb + 63 > qwb) {
                #pragma unroll
                for (int s = 0; s < 2; s++)
                    #pragma unroll
                    for (int r = 0; r < 16; r++) {
                        int kvg = kvb + s * 32 + (r & 3) + 8 * (r >> 2) + 4 * hi;
                        if (kvg > qg) sc[s][r] = -1e30f;
                    }
            }
            float ps = 0.f;
            #pragma unroll
            for (int s = 0; s < 2; s++)
                #pragma unroll
                for (int r = 0; r < 16; r++) {
                    float pv = exp2x(sc[s][r]);
                    sc[s][r] = pv;
                    ps += pv;
                }
            lsum += ps;
            #pragma unroll
            for (int c = 0; c < 4; c++) {
                const int s = c >> 1, rb_ = (c & 1) * 8;
                u32 a0 = cvtpk(sc[s][rb_ + 0], sc[s][rb_ + 1]);
                u32 a1 = cvtpk(sc[s][rb_ + 2], sc[s][rb_ + 3]);
                u32 b0 = cvtpk(sc[s][rb_ + 4], sc[s][rb_ + 5]);
                u32 b1 = cvtpk(sc[s][rb_ + 6], sc[s][rb_ + 7]);
                u32 X0 = hi ? a0 : b0, X1 = hi ? a1 : b1;
                u32 Y0 = (u32)__shfl_xor((int)X0, 32);
                u32 Y1 = (u32)__shfl_xor((int)X1, 32);
                uint4 pw;
                pw.x = hi ? Y0 : a0;
                pw.y = hi ? Y1 : a1;
                pw.z = hi ? b0 : Y0;
                pw.w = hi ? b1 : Y1;
                bfx8 pf = __builtin_bit_cast(bfx8, pw);
                __builtin_amdgcn_s_setprio(1);
                #pragma unroll
                for (int dt = 0; dt < 2; dt++) {
                    bfx8 vf = *reinterpret_cast<const bfx8*>(
                        &vbuf[bi][dt * 32 + l31][(c * 16 + hi * 8) ^ swz]);
                    cacc[dt] = __builtin_amdgcn_mfma_f32_32x32x16_bf16(pf, vf, cacc[dt], 0, 0, 0);
                }
                __builtin_amdgcn_s_setprio(0);
            }
        }
        if (tt + 2 < ntL) stage((tt + 2) % 3, (ti + 2) * 64);
    }

    float ltot = lsum + __shfl_xor(lsum, 32);
    if (!heavy) {
        float linv = 1.0f / ltot;
        #pragma unroll
        for (int r = 0; r < 16; r++) {
            const int qpat = (r & 3) + 8 * (r >> 2) + 4 * hi;
            float rl = __shfl(linv, qpat);
            const int q = qwb + qpat;
            #pragma unroll
            for (int dt = 0; dt < 2; dt++)
                ctx[((size_t)(bq * SEQ + q)) * D_OUT + hh * HDIM + dt * 32 + l31] =
                    f2bf(cacc[dt][r] * rl);
        }
    } else {
        const int qt4 = qt - 4;
        const int rbase = (qt4 * 32 + bh) * 256 + w * 32;
        if (hi == 0) { (part ? l1 : l0)[rbase + l31] = ltot; }
        #pragma unroll
        for (int r = 0; r < 16; r++) {
            const int qpat = (r & 3) + 8 * (r >> 2) + 4 * hi;
            const int q = qwb + qpat;
            #pragma unroll
            for (int dt = 0; dt < 2; dt++) {
                const int d = dt * 32 + l31;
                u16 val = f2bf(cacc[dt][r]);
                if (part == 0)
                    ctx[((size_t)(bq * SEQ + q)) * D_OUT + hh * HDIM + d] = val;
                else
                    o1[((size_t)(rbase + qpat)) * 64 + d] = val;
            }
        }
    }
}

// ---------------- combine heavy partials: ctx = (O0+O1)/(l0+l1) ----------------
__global__ void k_comb(u16* __restrict__ ctx, const u16* __restrict__ o1,
                       const float* __restrict__ l0, const float* __restrict__ l1) {
    int i = blockIdx.x * 256 + threadIdx.x;
    const int d    = (i & 7) * 8;
    const int qrow = (i >> 3) & 255;
    const int bi_  = i >> 11;
    const int bh   = bi_ & 31, qt4 = bi_ >> 5;
    const int bq = bh >> 4, hh = bh & 15;
    const int token = bq * SEQ + (4 + qt4) * 256 + qrow;
    const size_t cidx = (size_t)token * D_OUT + hh * HDIM + d;
    const int ridx = bi_ * 256 + qrow;
    const size_t oidx = (size_t)ridx * 64 + d;
    const float linv = 1.0f / (l0[ridx] + l1[ridx]);
    bfx8 a = *reinterpret_cast<const bfx8*>(&ctx[cidx]);
    bfx8 b = *reinterpret_cast<const bfx8*>(&o1[oidx]);
    bfx8 o;
    #pragma unroll
    for (int j = 0; j < 8; j++)
        o[j] = (short)f2bf((bf2f((u16)a[j]) + bf2f((u16)b[j])) * linv);
    *reinterpret_cast<bfx8*>(&ctx[cidx]) = o;
}

extern "C" void kernel_launch(void* const* d_in, const int* in_sizes, int n_in,
                              void* d_out, int out_size, void* d_ws, size_t ws_size,
                              hipStream_t stream) {
    const float* x  = (const float*)d_in[0];
    const float* Wq = (const float*)d_in[1];
    const float* Wk = (const float*)d_in[2];
    const float* Wv = (const float*)d_in[3];
    const float* Wo = (const float*)d_in[4];
    const float* bo = (const float*)d_in[5];
    float* out = (float*)d_out;

    char* ws = (char*)d_ws;
    u16* xb   = (u16*)(ws);                    //  8 MiB: x bf16 (reused for partials)
    u16* wt   = (u16*)(ws + (8u << 20));       //  8 MiB: W transposed bf16
    u16* qkvb = (u16*)(ws + (16u << 20));      // 24 MiB: Q,K [bh][s][d]; V^T [bh][d][s]
    u16* ctxb = (u16*)(ws + (40u << 20));      //  8 MiB: ctx bf16

    u16*   o1p = (u16*)(ws);                   // 4 MiB: part1 O bf16
    float* l0p = (float*)(ws + (4u << 20));    // 128 KiB
    float* l1p = (float*)(ws + (4u << 20) + (128u << 10));

    const u16* Qb  = qkvb;
    const u16* Kb  = qkvb + (size_t)M_TOT * D_OUT;
    const u16* Vtb = qkvb + (size_t)2 * M_TOT * D_OUT;

    k_conv_x <<<2048, 256, 0, stream>>>(x, xb);
    k_conv_wt<<<dim3(32, 32, 4), 256, 0, stream>>>(Wq, Wk, Wv, Wo, wt);
    k_qkv    <<<dim3(24, 32), 256, 0, stream>>>(xb, wt, qkvb);
    k_attn   <<<dim3(384), 512, 0, stream>>>(Qb, Kb, Vtb, ctxb, o1p, l0p, l1p);
    k_comb   <<<1024, 256, 0, stream>>>(ctxb, o1p, l0p, l1p);
    k_oproj  <<<dim3(16, 32), 256, 0, stream>>>(
        ctxb, wt + (size_t)3 * D_IN * D_OUT, bo, out);
}

// Round 20
// 109.341 us; speedup vs baseline: 1.0377x; 1.0164x over previous
//
#include <hip/hip_runtime.h>
#include <hip/hip_bf16.h>
#include <stdint.h>

#define D_IN   1024
#define D_OUT  1024
#define NHEAD  16
#define HDIM   64
#define SEQ    2048
#define BATCH  2
#define M_TOT  (BATCH*SEQ)   // 4096

typedef __attribute__((ext_vector_type(8)))  short bfx8;   // 8 bf16
typedef __attribute__((ext_vector_type(4)))  short bfx4;   // 4 bf16
typedef __attribute__((ext_vector_type(4)))  float fx4;
typedef __attribute__((ext_vector_type(16))) float fx16;
typedef unsigned short u16;
typedef unsigned int   u32;

__device__ __forceinline__ u16 f2bf(float f) {
    u32 u = __builtin_bit_cast(u32, f);
    u32 r = (u + 0x7FFFu + ((u >> 16) & 1u)) >> 16;   // RNE
    return (u16)r;
}
__device__ __forceinline__ float bf2f(u16 v) {
    u32 u = (u32)v << 16;
    return __builtin_bit_cast(float, u);
}

__device__ __forceinline__ u32 cvtpk(float lo, float hi) {
    u32 r;
    asm("v_cvt_pk_bf16_f32 %0, %1, %2" : "=v"(r) : "v"(lo), "v"(hi));
    return r;
}

__device__ __forceinline__ float exp2x(float x) {   // 2^x, single v_exp_f32
    float r;
    asm("v_exp_f32 %0, %1" : "=v"(r) : "v"(x));
    return r;
}

// async global -> LDS, 16B per lane. LDS dest = wave-uniform base + lane*16.
__device__ __forceinline__ void gload16(const u16* g, u16* l) {
    __builtin_amdgcn_global_load_lds(
        (const __attribute__((address_space(1))) void*)g,
        (__attribute__((address_space(3))) void*)l, 16, 0, 0);
}

// ---------------- merged input conversions ----------------
// blocks [0,2048): x fp32 -> bf16 (vectorized)
// blocks [2048,6144): W fp32 -> bf16 transposed; Wq pre-scaled 0.125*log2(e)
__global__ void k_conv(const float* __restrict__ x,
                       const float* __restrict__ Wq, const float* __restrict__ Wk,
                       const float* __restrict__ Wv, const float* __restrict__ Wo,
                       u16* __restrict__ xb, u16* __restrict__ wt) {
    __shared__ float tile[32][33];
    const int bid = blockIdx.x;
    if (bid < 2048) {
        int i = bid * 256 + threadIdx.x;
        const float4* s = reinterpret_cast<const float4*>(x);
        float4 a = s[2*i], b = s[2*i+1];
        uint4 o;
        o.x = (u32)f2bf(a.x) | ((u32)f2bf(a.y) << 16);
        o.y = (u32)f2bf(a.z) | ((u32)f2bf(a.w) << 16);
        o.z = (u32)f2bf(b.x) | ((u32)f2bf(b.y) << 16);
        o.w = (u32)f2bf(b.z) | ((u32)f2bf(b.w) << 16);
        reinterpret_cast<uint4*>(xb)[i] = o;
        return;
    }
    const int b2 = bid - 2048;
    const int wsel = b2 >> 10, rem = b2 & 1023;
    const int by = rem >> 5, bx = rem & 31;
    const float* W = (wsel == 0) ? Wq : (wsel == 1) ? Wk : (wsel == 2) ? Wv : Wo;
    const float scale = (wsel == 0) ? 0.125f * 1.4426950408889634f : 1.0f;
    u16* dst = wt + (size_t)wsel * D_IN * D_OUT;
    int r0 = by * 32, c0 = bx * 32;
    int tx = threadIdx.x & 31, ty = threadIdx.x >> 5;
    #pragma unroll
    for (int k = 0; k < 4; k++) {
        int i = ty + k * 8;
        tile[i][tx] = W[(size_t)(r0 + i) * D_OUT + c0 + tx];
    }
    __syncthreads();
    #pragma unroll
    for (int k = 0; k < 4; k++) {
        int i = ty + k * 8;
        dst[(size_t)(c0 + i) * D_IN + r0 + tx] = f2bf(tile[tx][i] * scale);
    }
}

// ---------------- 128x128 GEMM (m97 structure) — QKV ----------------
// Q,K head-split [proj][b*h][s][d] bf16 (32B-run coalesced stores).
// V (proj==2 blocks, blockIdx.x>=16): epilogue LDS-transpose -> V^T [bh][d][s]
// written as 16B/lane contiguous rows (kills the 8B x 4KB-stride scatter that
// caused ~24MB of L2 write-allocate RMW fetch, r18 FETCH_SIZE evidence).
__global__ __launch_bounds__(256) void k_qkv(const u16* __restrict__ A,
                                             const u16* __restrict__ Bt,
                                             u16* __restrict__ outb) {
    __shared__ u16 aL[128][32];
    __shared__ u16 bL[128][32];
    __shared__ u16 tb[64][132];       // V transpose buffer [d][s+pad]
    const int K = 1024;
    const int nb = blockIdx.x * 128, mb = blockIdx.y * 128;
    const int t = threadIdx.x, lane = t & 63, w = t >> 6;
    const int wr = w >> 1, wc = w & 1;
    const int li = lane & 15, lg = lane >> 4;
    const int srow = lane >> 2, schunk = (lane & 3) * 8;

    fx4 acc[4][4];
    #pragma unroll
    for (int i = 0; i < 4; i++)
        #pragma unroll
        for (int j = 0; j < 4; j++) acc[i][j] = fx4{0.f, 0.f, 0.f, 0.f};

    const u16* aBase = A  + (size_t)(mb + w * 32 + srow) * K + schunk;
    const u16* bBase = Bt + (size_t)(nb + w * 32 + srow) * K + schunk;

    for (int kb = 0; kb < K; kb += 32) {
        #pragma unroll
        for (int c = 0; c < 2; c++) {
            gload16(aBase + (size_t)c * 16 * K + kb, &aL[w * 32 + c * 16][0]);
            gload16(bBase + (size_t)c * 16 * K + kb, &bL[w * 32 + c * 16][0]);
        }
        __syncthreads();
        bfx8 af[4], bf[4];
        #pragma unroll
        for (int mi = 0; mi < 4; mi++)
            af[mi] = *reinterpret_cast<const bfx8*>(&aL[wr * 64 + mi * 16 + li][lg * 8]);
        #pragma unroll
        for (int ni = 0; ni < 4; ni++)
            bf[ni] = *reinterpret_cast<const bfx8*>(&bL[wc * 64 + ni * 16 + li][lg * 8]);
        #pragma unroll
        for (int mi = 0; mi < 4; mi++)
            #pragma unroll
            for (int ni = 0; ni < 4; ni++)
                acc[mi][ni] = __builtin_amdgcn_mfma_f32_16x16x32_bf16(af[mi], bf[ni], acc[mi][ni], 0, 0, 0);
        __syncthreads();
    }

    if (nb < 2048) {
        // Q / K: head-split store (unchanged)
        #pragma unroll
        for (int mi = 0; mi < 4; mi++) {
            #pragma unroll
            for (int ni = 0; ni < 4; ni++) {
                const int n = nb + wc * 64 + ni * 16 + li;
                const int m0 = mb + wr * 64 + mi * 16 + lg * 4;
                const int proj = n >> 10, h = (n >> 6) & 15, d = n & 63;
                const int b = m0 >> 11, s0 = m0 & 2047;
                u16* op = outb + (size_t)proj * M_TOT * D_OUT;
                #pragma unroll
                for (int r = 0; r < 4; r++)
                    op[((size_t)(b * NHEAD + h) * SEQ + s0 + r) * HDIM + d] =
                        f2bf(acc[mi][ni][r]);
            }
        }
    } else {
        // V: two head-halves, LDS transpose then coalesced V^T rows
        const int b = mb >> 11, sb = mb & 2047;
        const int h0 = (nb - 2048) >> 6;
        u16* vt = outb + (size_t)2 * M_TOT * D_OUT;
        #pragma unroll
        for (int hf = 0; hf < 2; hf++) {
            if (wc == hf) {
                #pragma unroll
                for (int ni = 0; ni < 4; ni++) {
                    const int d = ni * 16 + li;
                    #pragma unroll
                    for (int mi = 0; mi < 4; mi++) {
                        const int m0 = wr * 64 + mi * 16 + lg * 4;
                        bfx4 pk = {(short)f2bf(acc[mi][ni][0]), (short)f2bf(acc[mi][ni][1]),
                                   (short)f2bf(acc[mi][ni][2]), (short)f2bf(acc[mi][ni][3])};
                        *reinterpret_cast<bfx4*>(&tb[d][m0]) = pk;
                    }
                }
            }
            __syncthreads();
            const int h = h0 + hf;
            const int d = lane;                 // 0..63 (lane spans full wave? no: lane 0..63 ✓)
            u16* vrow = vt + (((size_t)(b * NHEAD + h) * HDIM + d) * SEQ) + sb;
            #pragma unroll
            for (int i = 0; i < 4; i++) {
                const int j = w + i * 4;        // 16 chunks of 8 s, 4 waves x 4
                *reinterpret_cast<bfx8*>(&vrow[j * 8]) =
                    *reinterpret_cast<const bfx8*>(&tb[d][j * 8]);
            }
            __syncthreads();
        }
    }
}

// ---------------- output projection: 128(M) x 64(N) tiles ----------------
__global__ __launch_bounds__(256) void k_oproj(const u16* __restrict__ A,
                                               const u16* __restrict__ Bt,
                                               const float* __restrict__ bias,
                                               float* __restrict__ outf) {
    __shared__ u16 aL[128][32];
    __shared__ u16 bL[64][32];
    const int K = 1024;
    const int nb = blockIdx.x * 64, mb = blockIdx.y * 128;
    const int t = threadIdx.x, lane = t & 63, w = t >> 6;
    const int wr = w >> 1, wc = w & 1;
    const int li = lane & 15, lg = lane >> 4;
    const int srow = lane >> 2, schunk = (lane & 3) * 8;

    fx4 acc[4][2];
    #pragma unroll
    for (int i = 0; i < 4; i++)
        #pragma unroll
        for (int j = 0; j < 2; j++) acc[i][j] = fx4{0.f, 0.f, 0.f, 0.f};

    const u16* aBase = A  + (size_t)(mb + w * 32 + srow) * K + schunk;
    const u16* bBase = Bt + (size_t)(nb + w * 16 + srow) * K + schunk;

    for (int kb = 0; kb < K; kb += 32) {
        gload16(aBase + kb,          &aL[w * 32][0]);
        gload16(aBase + 16 * K + kb, &aL[w * 32 + 16][0]);
        gload16(bBase + kb,          &bL[w * 16][0]);
        __syncthreads();
        bfx8 af[4], bf[2];
        #pragma unroll
        for (int mi = 0; mi < 4; mi++)
            af[mi] = *reinterpret_cast<const bfx8*>(&aL[wr * 64 + mi * 16 + li][lg * 8]);
        #pragma unroll
        for (int ni = 0; ni < 2; ni++)
            bf[ni] = *reinterpret_cast<const bfx8*>(&bL[wc * 32 + ni * 16 + li][lg * 8]);
        #pragma unroll
        for (int mi = 0; mi < 4; mi++)
            #pragma unroll
            for (int ni = 0; ni < 2; ni++)
                acc[mi][ni] = __builtin_amdgcn_mfma_f32_16x16x32_bf16(af[mi], bf[ni], acc[mi][ni], 0, 0, 0);
        __syncthreads();
    }

    #pragma unroll
    for (int mi = 0; mi < 4; mi++) {
        #pragma unroll
        for (int ni = 0; ni < 2; ni++) {
            const int n = nb + wc * 32 + ni * 16 + li;
            const int m0 = mb + wr * 64 + mi * 16 + lg * 4;
            const float bv = bias[n];
            #pragma unroll
            for (int r = 0; r < 4; r++)
                outf[(size_t)(m0 + r) * D_OUT + n] = acc[mi][ni][r] + bv;
        }
    }
}

// ---------------- causal flash attention (8-wave, 3-buffer, 1 barrier/tile) ------
__global__ __launch_bounds__(512, 2) void k_attn(const u16* __restrict__ Q,
                                                 const u16* __restrict__ Kp,
                                                 const u16* __restrict__ Vt,
                                                 u16* __restrict__ ctx,
                                                 u16* __restrict__ o1,
                                                 float* __restrict__ l0,
                                                 float* __restrict__ l1) {
    __shared__ u16 kbuf[3][64][64];   // K tile [kv][d], swizzled slots (24KB)
    __shared__ u16 vbuf[3][64][64];   // V^T tile [d][kv], swizzled slots (24KB)

    static const __constant__ signed char QT[12]   = {7,7,6,6,5,5,4,4,3,2,1,0};
    static const __constant__ signed char PART[12] = {0,1,0,1,0,1,0,1,0,0,0,0};

    const int g  = blockIdx.x;                   // 0..383
    const int m  = g & 31, pp = g >> 5;          // pp 0..11
    const int bh = (m & 7) * 4 + (m >> 3);       // 4 heads per XCD
    const int qt = QT[pp], part = PART[pp];
    const bool heavy = (qt >= 4);
    const int nt = 4 * qt + 4;
    int t0, t1;
    if (heavy) { int h1 = nt >> 1; t0 = part ? h1 : 0; t1 = part ? nt : h1; }
    else       { t0 = 0; t1 = nt; }
    const int ntL = t1 - t0;                     // <= 16

    const size_t base = (size_t)bh * SEQ * HDIM;
    const int t = threadIdx.x, lane = t & 63, w = t >> 6;   // w 0..7
    const int l31 = lane & 31, hi = lane >> 5;
    const int srow = lane >> 3;
    const int ts = (lane & 7) ^ srow;
    const int bq = bh >> 4, hh = bh & 15;
    const int swz = (l31 & 7) * 8;
    const int qwb = qt * 256 + w * 32;
    const int qg  = qwb + l31;

    auto stage = [&](int bi, int kvb) {
        const int rb = w * 8;
        gload16(Kp + base + (size_t)(kvb + rb + srow) * HDIM + ts * 8,
                &kbuf[bi][rb][0]);
        gload16(Vt + base + (size_t)(rb + srow) * SEQ + kvb + ts * 8,
                &vbuf[bi][rb][0]);
    };

    bfx8 qf[4];
    #pragma unroll
    for (int dc = 0; dc < 4; dc++)
        qf[dc] = *reinterpret_cast<const bfx8*>(
            &Q[base + (size_t)qg * HDIM + dc * 16 + hi * 8]);
    fx16 cacc[2];
    #pragma unroll
    for (int dt = 0; dt < 2; dt++)
        #pragma unroll
        for (int r = 0; r < 16; r++) cacc[dt][r] = 0.f;
    float lsum = 0.f;

    stage(0, t0 * 64);
    if (ntL > 1) stage(1, (t0 + 1) * 64);

    for (int tt = 0; tt < ntL; tt++) {
        const int ti = t0 + tt, kvb = ti * 64;
        if (tt + 1 < ntL) {
            asm volatile("s_waitcnt vmcnt(2)" ::: "memory");  // stage(tt) landed
        } else {
            asm volatile("s_waitcnt vmcnt(0)" ::: "memory");
        }
        __builtin_amdgcn_s_barrier();
        __builtin_amdgcn_sched_barrier(0);
        const int bi = tt % 3;
        if (kvb <= qwb + 31) {                   // wave-level causal skip
            fx16 sc[2];
            __builtin_amdgcn_s_setprio(1);
            #pragma unroll
            for (int s = 0; s < 2; s++) {
                #pragma unroll
                for (int r = 0; r < 16; r++) sc[s][r] = 0.f;
                #pragma unroll
                for (int dc = 0; dc < 4; dc++) {
                    bfx8 kf = *reinterpret_cast<const bfx8*>(
                        &kbuf[bi][s * 32 + l31][(dc * 16 + hi * 8) ^ swz]);
                    sc[s] = __builtin_amdgcn_mfma_f32_32x32x16_bf16(kf, qf[dc], sc[s], 0, 0, 0);
                }
            }
            __builtin_amdgcn_s_setprio(0);
            if (kvb + 63 > qwb) {
                #pragma unroll
                for (int s = 0; s < 2; s++)
                    #pragma unroll
                    for (int r = 0; r < 16; r++) {
                        int kvg = kvb + s * 32 + (r & 3) + 8 * (r >> 2) + 4 * hi;
                        if (kvg > qg) sc[s][r] = -1e30f;
                    }
            }
            float ps = 0.f;
            #pragma unroll
            for (int s = 0; s < 2; s++)
                #pragma unroll
                for (int r = 0; r < 16; r++) {
                    float pv = exp2x(sc[s][r]);
                    sc[s][r] = pv;
                    ps += pv;
                }
            lsum += ps;
            #pragma unroll
            for (int c = 0; c < 4; c++) {
                const int s = c >> 1, rb_ = (c & 1) * 8;
                u32 a0 = cvtpk(sc[s][rb_ + 0], sc[s][rb_ + 1]);
                u32 a1 = cvtpk(sc[s][rb_ + 2], sc[s][rb_ + 3]);
                u32 b0 = cvtpk(sc[s][rb_ + 4], sc[s][rb_ + 5]);
                u32 b1 = cvtpk(sc[s][rb_ + 6], sc[s][rb_ + 7]);
                u32 X0 = hi ? a0 : b0, X1 = hi ? a1 : b1;
                u32 Y0 = (u32)__shfl_xor((int)X0, 32);
                u32 Y1 = (u32)__shfl_xor((int)X1, 32);
                uint4 pw;
                pw.x = hi ? Y0 : a0;
                pw.y = hi ? Y1 : a1;
                pw.z = hi ? b0 : Y0;
                pw.w = hi ? b1 : Y1;
                bfx8 pf = __builtin_bit_cast(bfx8, pw);
                __builtin_amdgcn_s_setprio(1);
                #pragma unroll
                for (int dt = 0; dt < 2; dt++) {
                    bfx8 vf = *reinterpret_cast<const bfx8*>(
                        &vbuf[bi][dt * 32 + l31][(c * 16 + hi * 8) ^ swz]);
                    cacc[dt] = __builtin_amdgcn_mfma_f32_32x32x16_bf16(pf, vf, cacc[dt], 0, 0, 0);
                }
                __builtin_amdgcn_s_setprio(0);
            }
        }
        if (tt + 2 < ntL) stage((tt + 2) % 3, (ti + 2) * 64);
    }

    float ltot = lsum + __shfl_xor(lsum, 32);
    if (!heavy) {
        float linv = 1.0f / ltot;
        #pragma unroll
        for (int r = 0; r < 16; r++) {
            const int qpat = (r & 3) + 8 * (r >> 2) + 4 * hi;
            float rl = __shfl(linv, qpat);
            const int q = qwb + qpat;
            #pragma unroll
            for (int dt = 0; dt < 2; dt++)
                ctx[((size_t)(bq * SEQ + q)) * D_OUT + hh * HDIM + dt * 32 + l31] =
                    f2bf(cacc[dt][r] * rl);
        }
    } else {
        const int qt4 = qt - 4;
        const int rbase = (qt4 * 32 + bh) * 256 + w * 32;
        if (hi == 0) { (part ? l1 : l0)[rbase + l31] = ltot; }
        #pragma unroll
        for (int r = 0; r < 16; r++) {
            const int qpat = (r & 3) + 8 * (r >> 2) + 4 * hi;
            const int q = qwb + qpat;
            #pragma unroll
            for (int dt = 0; dt < 2; dt++) {
                const int d = dt * 32 + l31;
                u16 val = f2bf(cacc[dt][r]);
                if (part == 0)
                    ctx[((size_t)(bq * SEQ + q)) * D_OUT + hh * HDIM + d] = val;
                else
                    o1[((size_t)(rbase + qpat)) * 64 + d] = val;
            }
        }
    }
}

// ---------------- combine heavy partials: ctx = (O0+O1)/(l0+l1) ----------------
__global__ void k_comb(u16* __restrict__ ctx, const u16* __restrict__ o1,
                       const float* __restrict__ l0, const float* __restrict__ l1) {
    int i = blockIdx.x * 256 + threadIdx.x;
    const int d    = (i & 7) * 8;
    const int qrow = (i >> 3) & 255;
    const int bi_  = i >> 11;
    const int bh   = bi_ & 31, qt4 = bi_ >> 5;
    const int bq = bh >> 4, hh = bh & 15;
    const int token = bq * SEQ + (4 + qt4) * 256 + qrow;
    const size_t cidx = (size_t)token * D_OUT + hh * HDIM + d;
    const int ridx = bi_ * 256 + qrow;
    const size_t oidx = (size_t)ridx * 64 + d;
    const float linv = 1.0f / (l0[ridx] + l1[ridx]);
    bfx8 a = *reinterpret_cast<const bfx8*>(&ctx[cidx]);
    bfx8 b = *reinterpret_cast<const bfx8*>(&o1[oidx]);
    bfx8 o;
    #pragma unroll
    for (int j = 0; j < 8; j++)
        o[j] = (short)f2bf((bf2f((u16)a[j]) + bf2f((u16)b[j])) * linv);
    *reinterpret_cast<bfx8*>(&ctx[cidx]) = o;
}

extern "C" void kernel_launch(void* const* d_in, const int* in_sizes, int n_in,
                              void* d_out, int out_size, void* d_ws, size_t ws_size,
                              hipStream_t stream) {
    const float* x  = (const float*)d_in[0];
    const float* Wq = (const float*)d_in[1];
    const float* Wk = (const float*)d_in[2];
    const float* Wv = (const float*)d_in[3];
    const float* Wo = (const float*)d_in[4];
    const float* bo = (const float*)d_in[5];
    float* out = (float*)d_out;

    char* ws = (char*)d_ws;
    u16* xb   = (u16*)(ws);                    //  8 MiB: x bf16 (reused for partials)
    u16* wt   = (u16*)(ws + (8u << 20));       //  8 MiB: W transposed bf16
    u16* qkvb = (u16*)(ws + (16u << 20));      // 24 MiB: Q,K [bh][s][d]; V^T [bh][d][s]
    u16* ctxb = (u16*)(ws + (40u << 20));      //  8 MiB: ctx bf16

    u16*   o1p = (u16*)(ws);                   // 4 MiB: part1 O bf16
    float* l0p = (float*)(ws + (4u << 20));    // 128 KiB
    float* l1p = (float*)(ws + (4u << 20) + (128u << 10));

    const u16* Qb  = qkvb;
    const u16* Kb  = qkvb + (size_t)M_TOT * D_OUT;
    const u16* Vtb = qkvb + (size_t)2 * M_TOT * D_OUT;

    k_conv  <<<6144, 256, 0, stream>>>(x, Wq, Wk, Wv, Wo, xb, wt);
    k_qkv   <<<dim3(24, 32), 256, 0, stream>>>(xb, wt, qkvb);
    k_attn  <<<dim3(384), 512, 0, stream>>>(Qb, Kb, Vtb, ctxb, o1p, l0p, l1p);
    k_comb  <<<1024, 256, 0, stream>>>(ctxb, o1p, l0p, l1p);
    k_oproj <<<dim3(16, 32), 256, 0, stream>>>(
        ctxb, wt + (size_t)3 * D_IN * D_OUT, bo, out);
}

// Round 21
// 100.900 us; speedup vs baseline: 1.1245x; 1.0837x over previous
//
#include <hip/hip_runtime.h>
#include <hip/hip_bf16.h>
#include <stdint.h>

#define D_IN   1024
#define D_OUT  1024
#define NHEAD  16
#define HDIM   64
#define SEQ    2048
#define BATCH  2
#define M_TOT  (BATCH*SEQ)   // 4096

typedef __attribute__((ext_vector_type(8)))  short bfx8;   // 8 bf16
typedef __attribute__((ext_vector_type(4)))  short bfx4;   // 4 bf16
typedef __attribute__((ext_vector_type(4)))  float fx4;
typedef __attribute__((ext_vector_type(16))) float fx16;
typedef unsigned short u16;
typedef unsigned int   u32;

__device__ __forceinline__ u16 f2bf(float f) {
    u32 u = __builtin_bit_cast(u32, f);
    u32 r = (u + 0x7FFFu + ((u >> 16) & 1u)) >> 16;   // RNE
    return (u16)r;
}
__device__ __forceinline__ float bf2f(u16 v) {
    u32 u = (u32)v << 16;
    return __builtin_bit_cast(float, u);
}

__device__ __forceinline__ u32 cvtpk(float lo, float hi) {
    u32 r;
    asm("v_cvt_pk_bf16_f32 %0, %1, %2" : "=v"(r) : "v"(lo), "v"(hi));
    return r;
}

__device__ __forceinline__ float exp2x(float x) {   // 2^x, single v_exp_f32
    float r;
    asm("v_exp_f32 %0, %1" : "=v"(r) : "v"(x));
    return r;
}

// async global -> LDS, 16B per lane. LDS dest = wave-uniform base + lane*16.
__device__ __forceinline__ void gload16(const u16* g, u16* l) {
    __builtin_amdgcn_global_load_lds(
        (const __attribute__((address_space(1))) void*)g,
        (__attribute__((address_space(3))) void*)l, 16, 0, 0);
}

// ---------------- merged input conversions ----------------
__global__ void k_conv(const float* __restrict__ x,
                       const float* __restrict__ Wq, const float* __restrict__ Wk,
                       const float* __restrict__ Wv, const float* __restrict__ Wo,
                       u16* __restrict__ xb, u16* __restrict__ wt) {
    __shared__ float tile[32][33];
    const int bid = blockIdx.x;
    if (bid < 2048) {
        int i = bid * 256 + threadIdx.x;
        const float4* s = reinterpret_cast<const float4*>(x);
        float4 a = s[2*i], b = s[2*i+1];
        uint4 o;
        o.x = (u32)f2bf(a.x) | ((u32)f2bf(a.y) << 16);
        o.y = (u32)f2bf(a.z) | ((u32)f2bf(a.w) << 16);
        o.z = (u32)f2bf(b.x) | ((u32)f2bf(b.y) << 16);
        o.w = (u32)f2bf(b.z) | ((u32)f2bf(b.w) << 16);
        reinterpret_cast<uint4*>(xb)[i] = o;
        return;
    }
    const int b2 = bid - 2048;
    const int wsel = b2 >> 10, rem = b2 & 1023;
    const int by = rem >> 5, bx = rem & 31;
    const float* W = (wsel == 0) ? Wq : (wsel == 1) ? Wk : (wsel == 2) ? Wv : Wo;
    const float scale = (wsel == 0) ? 0.125f * 1.4426950408889634f : 1.0f;
    u16* dst = wt + (size_t)wsel * D_IN * D_OUT;
    int r0 = by * 32, c0 = bx * 32;
    int tx = threadIdx.x & 31, ty = threadIdx.x >> 5;
    #pragma unroll
    for (int k = 0; k < 4; k++) {
        int i = ty + k * 8;
        tile[i][tx] = W[(size_t)(r0 + i) * D_OUT + c0 + tx];
    }
    __syncthreads();
    #pragma unroll
    for (int k = 0; k < 4; k++) {
        int i = ty + k * 8;
        dst[(size_t)(c0 + i) * D_IN + r0 + tx] = f2bf(tile[tx][i] * scale);
    }
}

// ---------------- 128x128 GEMM (m97 structure) — QKV ----------------
__global__ __launch_bounds__(256) void k_qkv(const u16* __restrict__ A,
                                             const u16* __restrict__ Bt,
                                             u16* __restrict__ outb) {
    __shared__ u16 aL[128][32];
    __shared__ u16 bL[128][32];
    __shared__ u16 tb[64][132];       // V transpose buffer [d][s+pad]
    const int K = 1024;
    const int nb = blockIdx.x * 128, mb = blockIdx.y * 128;
    const int t = threadIdx.x, lane = t & 63, w = t >> 6;
    const int wr = w >> 1, wc = w & 1;
    const int li = lane & 15, lg = lane >> 4;
    const int srow = lane >> 2, schunk = (lane & 3) * 8;

    fx4 acc[4][4];
    #pragma unroll
    for (int i = 0; i < 4; i++)
        #pragma unroll
        for (int j = 0; j < 4; j++) acc[i][j] = fx4{0.f, 0.f, 0.f, 0.f};

    const u16* aBase = A  + (size_t)(mb + w * 32 + srow) * K + schunk;
    const u16* bBase = Bt + (size_t)(nb + w * 32 + srow) * K + schunk;

    for (int kb = 0; kb < K; kb += 32) {
        #pragma unroll
        for (int c = 0; c < 2; c++) {
            gload16(aBase + (size_t)c * 16 * K + kb, &aL[w * 32 + c * 16][0]);
            gload16(bBase + (size_t)c * 16 * K + kb, &bL[w * 32 + c * 16][0]);
        }
        __syncthreads();
        bfx8 af[4], bf[4];
        #pragma unroll
        for (int mi = 0; mi < 4; mi++)
            af[mi] = *reinterpret_cast<const bfx8*>(&aL[wr * 64 + mi * 16 + li][lg * 8]);
        #pragma unroll
        for (int ni = 0; ni < 4; ni++)
            bf[ni] = *reinterpret_cast<const bfx8*>(&bL[wc * 64 + ni * 16 + li][lg * 8]);
        #pragma unroll
        for (int mi = 0; mi < 4; mi++)
            #pragma unroll
            for (int ni = 0; ni < 4; ni++)
                acc[mi][ni] = __builtin_amdgcn_mfma_f32_16x16x32_bf16(af[mi], bf[ni], acc[mi][ni], 0, 0, 0);
        __syncthreads();
    }

    if (nb < 2048) {
        #pragma unroll
        for (int mi = 0; mi < 4; mi++) {
            #pragma unroll
            for (int ni = 0; ni < 4; ni++) {
                const int n = nb + wc * 64 + ni * 16 + li;
                const int m0 = mb + wr * 64 + mi * 16 + lg * 4;
                const int proj = n >> 10, h = (n >> 6) & 15, d = n & 63;
                const int b = m0 >> 11, s0 = m0 & 2047;
                u16* op = outb + (size_t)proj * M_TOT * D_OUT;
                #pragma unroll
                for (int r = 0; r < 4; r++)
                    op[((size_t)(b * NHEAD + h) * SEQ + s0 + r) * HDIM + d] =
                        f2bf(acc[mi][ni][r]);
            }
        }
    } else {
        // V: two head-halves, LDS transpose then coalesced V^T rows
        const int b = mb >> 11, sb = mb & 2047;
        const int h0 = (nb - 2048) >> 6;
        u16* vt = outb + (size_t)2 * M_TOT * D_OUT;
        #pragma unroll
        for (int hf = 0; hf < 2; hf++) {
            if (wc == hf) {
                #pragma unroll
                for (int ni = 0; ni < 4; ni++) {
                    const int d = ni * 16 + li;
                    #pragma unroll
                    for (int mi = 0; mi < 4; mi++) {
                        const int m0 = wr * 64 + mi * 16 + lg * 4;
                        bfx4 pk = {(short)f2bf(acc[mi][ni][0]), (short)f2bf(acc[mi][ni][1]),
                                   (short)f2bf(acc[mi][ni][2]), (short)f2bf(acc[mi][ni][3])};
                        *reinterpret_cast<bfx4*>(&tb[d][m0]) = pk;
                    }
                }
            }
            __syncthreads();
            const int h = h0 + hf;
            const int d = lane;
            u16* vrow = vt + (((size_t)(b * NHEAD + h) * HDIM + d) * SEQ) + sb;
            #pragma unroll
            for (int i = 0; i < 4; i++) {
                const int j = w + i * 4;
                *reinterpret_cast<bfx8*>(&vrow[j * 8]) =
                    *reinterpret_cast<const bfx8*>(&tb[d][j * 8]);
            }
            __syncthreads();
        }
    }
}

// ---------------- output projection: 128(M) x 64(N) tiles ----------------
__global__ __launch_bounds__(256) void k_oproj(const u16* __restrict__ A,
                                               const u16* __restrict__ Bt,
                                               const float* __restrict__ bias,
                                               float* __restrict__ outf) {
    __shared__ u16 aL[128][32];
    __shared__ u16 bL[64][32];
    const int K = 1024;
    const int nb = blockIdx.x * 64, mb = blockIdx.y * 128;
    const int t = threadIdx.x, lane = t & 63, w = t >> 6;
    const int wr = w >> 1, wc = w & 1;
    const int li = lane & 15, lg = lane >> 4;
    const int srow = lane >> 2, schunk = (lane & 3) * 8;

    fx4 acc[4][2];
    #pragma unroll
    for (int i = 0; i < 4; i++)
        #pragma unroll
        for (int j = 0; j < 2; j++) acc[i][j] = fx4{0.f, 0.f, 0.f, 0.f};

    const u16* aBase = A  + (size_t)(mb + w * 32 + srow) * K + schunk;
    const u16* bBase = Bt + (size_t)(nb + w * 16 + srow) * K + schunk;

    for (int kb = 0; kb < K; kb += 32) {
        gload16(aBase + kb,          &aL[w * 32][0]);
        gload16(aBase + 16 * K + kb, &aL[w * 32 + 16][0]);
        gload16(bBase + kb,          &bL[w * 16][0]);
        __syncthreads();
        bfx8 af[4], bf[2];
        #pragma unroll
        for (int mi = 0; mi < 4; mi++)
            af[mi] = *reinterpret_cast<const bfx8*>(&aL[wr * 64 + mi * 16 + li][lg * 8]);
        #pragma unroll
        for (int ni = 0; ni < 2; ni++)
            bf[ni] = *reinterpret_cast<const bfx8*>(&bL[wc * 32 + ni * 16 + li][lg * 8]);
        #pragma unroll
        for (int mi = 0; mi < 4; mi++)
            #pragma unroll
            for (int ni = 0; ni < 2; ni++)
                acc[mi][ni] = __builtin_amdgcn_mfma_f32_16x16x32_bf16(af[mi], bf[ni], acc[mi][ni], 0, 0, 0);
        __syncthreads();
    }

    #pragma unroll
    for (int mi = 0; mi < 4; mi++) {
        #pragma unroll
        for (int ni = 0; ni < 2; ni++) {
            const int n = nb + wc * 32 + ni * 16 + li;
            const int m0 = mb + wr * 64 + mi * 16 + lg * 4;
            const float bv = bias[n];
            #pragma unroll
            for (int r = 0; r < 4; r++)
                outf[(size_t)(m0 + r) * D_OUT + n] = acc[mi][ni][r] + bv;
        }
    }
}

// ---------------- causal flash attention: equal-weight partition ----------------
// 480 blocks = 15 parts/bh with sizes in [4,12] (most 8-12) -> per-CU load is
// balanced under ANY dispatch (the r20 ordering put 32 tile-units on some CUs
// vs 10 on others). Multi-part q-tiles (qt>=3, 2-3 parts) combine by ADDITION:
// part0 -> ctx unnorm + l0; parts 1,2 -> packed extra slots; k_comb divides by
// total l. qt<=2 (single part) writes normalized directly.
__global__ __launch_bounds__(512, 2) void k_attn(const u16* __restrict__ Q,
                                                 const u16* __restrict__ Kp,
                                                 const u16* __restrict__ Vt,
                                                 u16* __restrict__ ctx,
                                                 u16* __restrict__ oE,
                                                 float* __restrict__ l0v,
                                                 float* __restrict__ lE) {
    __shared__ u16 kbuf[3][64][64];   // K tile [kv][d], swizzled slots
    __shared__ u16 vbuf[3][64][64];   // V^T tile [d][kv], swizzled slots

    // 15 parts/bh: qt7:{0-11,11-22,22-32} qt6:{0-10,10-19,19-28} qt5:{0-12,12-24}
    // qt4:{0-10,10-20} qt3:{0-8,8-16} qt2:{0-12} qt1:{0-8} qt0:{0-4}; heaviest-first.
    static const __constant__ signed char PPQT[15]   = {7,7,7,6,6,6,5,5,4,4,3,3,2,1,0};
    static const __constant__ signed char PPT0[15]   = {0,11,22,0,10,19,0,12,0,10,0,8,0,0,0};
    static const __constant__ signed char PPT1[15]   = {11,22,32,10,19,28,12,24,10,20,8,16,12,8,4};
    static const __constant__ signed char PPPART[15] = {0,1,2,0,1,2,0,1,0,1,0,1,0,0,0};
    static const __constant__ signed char ORDER[15]  = {6,7,12,0,1,2,3,8,9,4,5,10,11,13,14};

    const int g  = blockIdx.x;                   // 0..479
    const int m  = g & 31, pp = ORDER[g >> 5];
    const int bh = (m & 7) * 4 + (m >> 3);       // 4 heads per XCD
    const int qt = PPQT[pp], part = PPPART[pp];
    const int t0 = PPT0[pp], t1 = PPT1[pp];
    const int ntL = t1 - t0;                     // <= 12

    const size_t base = (size_t)bh * SEQ * HDIM;
    const int t = threadIdx.x, lane = t & 63, w = t >> 6;   // w 0..7
    const int l31 = lane & 31, hi = lane >> 5;
    const int srow = lane >> 3;
    const int ts = (lane & 7) ^ srow;
    const int bq = bh >> 4, hh = bh & 15;
    const int swz = (l31 & 7) * 8;
    const int qwb = qt * 256 + w * 32;
    const int qg  = qwb + l31;

    auto stage = [&](int bi, int kvb) {
        const int rb = w * 8;
        gload16(Kp + base + (size_t)(kvb + rb + srow) * HDIM + ts * 8,
                &kbuf[bi][rb][0]);
        gload16(Vt + base + (size_t)(rb + srow) * SEQ + kvb + ts * 8,
                &vbuf[bi][rb][0]);
    };

    bfx8 qf[4];
    #pragma unroll
    for (int dc = 0; dc < 4; dc++)
        qf[dc] = *reinterpret_cast<const bfx8*>(
            &Q[base + (size_t)qg * HDIM + dc * 16 + hi * 8]);
    fx16 cacc[2];
    #pragma unroll
    for (int dt = 0; dt < 2; dt++)
        #pragma unroll
        for (int r = 0; r < 16; r++) cacc[dt][r] = 0.f;
    float lsum = 0.f;

    stage(0, t0 * 64);
    if (ntL > 1) stage(1, (t0 + 1) * 64);

    for (int tt = 0; tt < ntL; tt++) {
        const int ti = t0 + tt, kvb = ti * 64;
        if (tt + 1 < ntL) {
            asm volatile("s_waitcnt vmcnt(2)" ::: "memory");  // stage(tt) landed
        } else {
            asm volatile("s_waitcnt vmcnt(0)" ::: "memory");
        }
        __builtin_amdgcn_s_barrier();
        __builtin_amdgcn_sched_barrier(0);
        const int bi = tt % 3;
        if (kvb <= qwb + 31) {                   // wave-level causal skip
            fx16 sc[2];
            __builtin_amdgcn_s_setprio(1);
            #pragma unroll
            for (int s = 0; s < 2; s++) {
                #pragma unroll
                for (int r = 0; r < 16; r++) sc[s][r] = 0.f;
                #pragma unroll
                for (int dc = 0; dc < 4; dc++) {
                    bfx8 kf = *reinterpret_cast<const bfx8*>(
                        &kbuf[bi][s * 32 + l31][(dc * 16 + hi * 8) ^ swz]);
                    sc[s] = __builtin_amdgcn_mfma_f32_32x32x16_bf16(kf, qf[dc], sc[s], 0, 0, 0);
                }
            }
            __builtin_amdgcn_s_setprio(0);
            if (kvb + 63 > qwb) {
                #pragma unroll
                for (int s = 0; s < 2; s++)
                    #pragma unroll
                    for (int r = 0; r < 16; r++) {
                        int kvg = kvb + s * 32 + (r & 3) + 8 * (r >> 2) + 4 * hi;
                        if (kvg > qg) sc[s][r] = -1e30f;
                    }
            }
            float ps = 0.f;
            #pragma unroll
            for (int s = 0; s < 2; s++)
                #pragma unroll
                for (int r = 0; r < 16; r++) {
                    float pv = exp2x(sc[s][r]);
                    sc[s][r] = pv;
                    ps += pv;
                }
            lsum += ps;
            #pragma unroll
            for (int c = 0; c < 4; c++) {
                const int s = c >> 1, rb_ = (c & 1) * 8;
                u32 a0 = cvtpk(sc[s][rb_ + 0], sc[s][rb_ + 1]);
                u32 a1 = cvtpk(sc[s][rb_ + 2], sc[s][rb_ + 3]);
                u32 b0 = cvtpk(sc[s][rb_ + 4], sc[s][rb_ + 5]);
                u32 b1 = cvtpk(sc[s][rb_ + 6], sc[s][rb_ + 7]);
                u32 X0 = hi ? a0 : b0, X1 = hi ? a1 : b1;
                u32 Y0 = (u32)__shfl_xor((int)X0, 32);
                u32 Y1 = (u32)__shfl_xor((int)X1, 32);
                uint4 pw;
                pw.x = hi ? Y0 : a0;
                pw.y = hi ? Y1 : a1;
                pw.z = hi ? b0 : Y0;
                pw.w = hi ? b1 : Y1;
                bfx8 pf = __builtin_bit_cast(bfx8, pw);
                __builtin_amdgcn_s_setprio(1);
                #pragma unroll
                for (int dt = 0; dt < 2; dt++) {
                    bfx8 vf = *reinterpret_cast<const bfx8*>(
                        &vbuf[bi][dt * 32 + l31][(c * 16 + hi * 8) ^ swz]);
                    cacc[dt] = __builtin_amdgcn_mfma_f32_32x32x16_bf16(pf, vf, cacc[dt], 0, 0, 0);
                }
                __builtin_amdgcn_s_setprio(0);
            }
        }
        if (tt + 2 < ntL) stage((tt + 2) % 3, (ti + 2) * 64);
    }

    float ltot = lsum + __shfl_xor(lsum, 32);
    if (qt <= 2) {
        // single part: normalized direct write
        float linv = 1.0f / ltot;
        #pragma unroll
        for (int r = 0; r < 16; r++) {
            const int qpat = (r & 3) + 8 * (r >> 2) + 4 * hi;
            float rl = __shfl(linv, qpat);
            const int q = qwb + qpat;
            #pragma unroll
            for (int dt = 0; dt < 2; dt++)
                ctx[((size_t)(bq * SEQ + q)) * D_OUT + hh * HDIM + dt * 32 + l31] =
                    f2bf(cacc[dt][r] * rl);
        }
    } else if (part == 0) {
        // part0: ctx unnormalized + l0
        if (hi == 0) l0v[((bh * 5 + qt - 3) << 8) + w * 32 + l31] = ltot;
        #pragma unroll
        for (int r = 0; r < 16; r++) {
            const int qpat = (r & 3) + 8 * (r >> 2) + 4 * hi;
            const int q = qwb + qpat;
            #pragma unroll
            for (int dt = 0; dt < 2; dt++)
                ctx[((size_t)(bq * SEQ + q)) * D_OUT + hh * HDIM + dt * 32 + l31] =
                    f2bf(cacc[dt][r]);
        }
    } else {
        // extra part: packed slot. qt7:{p1->0,p2->1} qt6:{p1->2,p2->3} qt5->4 qt4->5 qt3->6
        const int slot = (qt == 7) ? (part - 1) : (qt == 6) ? (1 + part)
                        : (qt == 5) ? 4 : (qt == 4) ? 5 : 6;
        const int rbase = ((bh * 7 + slot) << 8);
        if (hi == 0) lE[rbase + w * 32 + l31] = ltot;
        #pragma unroll
        for (int r = 0; r < 16; r++) {
            const int qpat = (r & 3) + 8 * (r >> 2) + 4 * hi;
            #pragma unroll
            for (int dt = 0; dt < 2; dt++)
                oE[((size_t)(rbase + w * 32 + qpat)) * 64 + dt * 32 + l31] =
                    f2bf(cacc[dt][r]);
        }
    }
}

// ---------------- combine multi-part q-tiles: ctx = sum(O)/sum(l) ----------------
// covers qt 3..7 x 32 bh x 256 rows x 64 d
__global__ void k_comb(u16* __restrict__ ctx, const u16* __restrict__ oE,
                       const float* __restrict__ l0v, const float* __restrict__ lE) {
    int i = blockIdx.x * 256 + threadIdx.x;      // 327680 threads, 8 d-els each
    const int d    = (i & 7) * 8;
    const int row  = (i >> 3) & 255;
    const int idx  = i >> 11;                    // bh*5 + qq, 0..159
    const int bh   = idx / 5, qq = idx - bh * 5;
    const int qt   = qq + 3;
    const int bq = bh >> 4, hh = bh & 15;
    const int slot1 = (qt == 7) ? 0 : (qt == 6) ? 2 : (qt == 5) ? 4 : (qt == 4) ? 5 : 6;
    const bool three = (qt >= 6);
    const int q = qt * 256 + row;
    const size_t cidx = ((size_t)(bq * SEQ + q)) * D_OUT + hh * HDIM + d;
    const int r1 = ((bh * 7 + slot1) << 8) + row;
    float l = l0v[((bh * 5 + qq) << 8) + row] + lE[r1];
    bfx8 a = *reinterpret_cast<const bfx8*>(&ctx[cidx]);
    bfx8 b = *reinterpret_cast<const bfx8*>(&oE[(size_t)r1 * 64 + d]);
    float acc[8];
    #pragma unroll
    for (int j = 0; j < 8; j++) acc[j] = bf2f((u16)a[j]) + bf2f((u16)b[j]);
    if (three) {
        const int r2 = r1 + 256;
        l += lE[r2];
        bfx8 c = *reinterpret_cast<const bfx8*>(&oE[(size_t)r2 * 64 + d]);
        #pragma unroll
        for (int j = 0; j < 8; j++) acc[j] += bf2f((u16)c[j]);
    }
    const float linv = 1.0f / l;
    bfx8 o;
    #pragma unroll
    for (int j = 0; j < 8; j++) o[j] = (short)f2bf(acc[j] * linv);
    *reinterpret_cast<bfx8*>(&ctx[cidx]) = o;
}

extern "C" void kernel_launch(void* const* d_in, const int* in_sizes, int n_in,
                              void* d_out, int out_size, void* d_ws, size_t ws_size,
                              hipStream_t stream) {
    const float* x  = (const float*)d_in[0];
    const float* Wq = (const float*)d_in[1];
    const float* Wk = (const float*)d_in[2];
    const float* Wv = (const float*)d_in[3];
    const float* Wo = (const float*)d_in[4];
    const float* bo = (const float*)d_in[5];
    float* out = (float*)d_out;

    char* ws = (char*)d_ws;
    u16* xb   = (u16*)(ws);                    //  8 MiB: x bf16 (reused for partials)
    u16* wt   = (u16*)(ws + (8u << 20));       //  8 MiB: W transposed bf16
    u16* qkvb = (u16*)(ws + (16u << 20));      // 24 MiB: Q,K [bh][s][d]; V^T [bh][d][s]
    u16* ctxb = (u16*)(ws + (40u << 20));      //  8 MiB: ctx bf16

    // attn partial scratch inside xb region (xb consumed before attn runs)
    u16*   oEp = (u16*)(ws);                   // 32*7*256*64*2 = 7,340,032 B
    float* l0p = (float*)(ws + 7340032);       // 32*5*256*4   =   163,840 B
    float* lEp = (float*)(ws + 7503872);       // 32*7*256*4   =   229,376 B

    const u16* Qb  = qkvb;
    const u16* Kb  = qkvb + (size_t)M_TOT * D_OUT;
    const u16* Vtb = qkvb + (size_t)2 * M_TOT * D_OUT;

    k_conv  <<<6144, 256, 0, stream>>>(x, Wq, Wk, Wv, Wo, xb, wt);
    k_qkv   <<<dim3(24, 32), 256, 0, stream>>>(xb, wt, qkvb);
    k_attn  <<<dim3(480), 512, 0, stream>>>(Qb, Kb, Vtb, ctxb, oEp, l0p, lEp);
    k_comb  <<<1280, 256, 0, stream>>>(ctxb, oEp, l0p, lEp);
    k_oproj <<<dim3(16, 32), 256, 0, stream>>>(
        ctxb, wt + (size_t)3 * D_IN * D_OUT, bo, out);
}